// Round 1
// baseline (262.758 us; speedup 1.0000x reference)
//
#include <hip/hip_runtime.h>
#include <math.h>

#define BATCH 8
#define NPRED 8192
#define MPART 2048
#define NPTS  (BATCH * NPRED)   // 65536 points total
#define BASE_ALPHA 0.05f
#define EPS 1e-6f

// Zero both per-iteration batch-max slots (8 batches x 2 iterations).
__global__ __launch_bounds__(64) void init_bmax_kernel(unsigned* __restrict__ bmax) {
    if (threadIdx.x < 16) bmax[threadIdx.x] = 0u;
}

// One thread per query point: scan all M partial points, track min d^2 + argmin.
// All lanes in a wave share batch b and loop counter m -> partial loads are
// wave-uniform (expect s_load / scalar cache). 4 independent min-chains break
// the serial min dependency for ILP at 1 wave/SIMD occupancy.
__global__ __launch_bounds__(256) void nn_kernel(
    const float* __restrict__ src,      // [B,N,3] current refined positions
    const float* __restrict__ partial,  // [B,M,3]
    float* __restrict__ out_md,         // [B*N] min distance (sqrt'd)
    int*   __restrict__ out_idx,        // [B*N] argmin
    unsigned* __restrict__ bmax)        // [B] per-batch max(min_dist) as uint bits
{
    const int t = blockIdx.x * 256 + threadIdx.x;   // 0..65535
    const int b = t >> 13;                          // 8192 points per batch; uniform per block
    const float* p = src + 3u * (unsigned)t;
    const float ax = p[0], ay = p[1], az = p[2];
    const float* __restrict__ pb = partial + 3u * (unsigned)(b * MPART);

    float best0 = 1e30f, best1 = 1e30f, best2 = 1e30f, best3 = 1e30f;
    int   idx0 = 0, idx1 = 1, idx2 = 2, idx3 = 3;

    #pragma unroll 4
    for (int m = 0; m < MPART; m += 4) {
        const float* q = pb + 3 * m;
        {
            float dx = ax - q[0], dy = ay - q[1], dz = az - q[2];
            float d2 = fmaf(dx, dx, fmaf(dy, dy, dz * dz));
            if (d2 < best0) { best0 = d2; idx0 = m; }
        }
        {
            float dx = ax - q[3], dy = ay - q[4], dz = az - q[5];
            float d2 = fmaf(dx, dx, fmaf(dy, dy, dz * dz));
            if (d2 < best1) { best1 = d2; idx1 = m + 1; }
        }
        {
            float dx = ax - q[6], dy = ay - q[7], dz = az - q[8];
            float d2 = fmaf(dx, dx, fmaf(dy, dy, dz * dz));
            if (d2 < best2) { best2 = d2; idx2 = m + 2; }
        }
        {
            float dx = ax - q[9], dy = ay - q[10], dz = az - q[11];
            float d2 = fmaf(dx, dx, fmaf(dy, dy, dz * dz));
            if (d2 < best3) { best3 = d2; idx3 = m + 3; }
        }
    }

    // Lexicographic merge (value, index) preserves jnp.argmin first-occurrence.
    float bv = best0; int bi = idx0;
    if (best1 < bv || (best1 == bv && idx1 < bi)) { bv = best1; bi = idx1; }
    if (best2 < bv || (best2 == bv && idx2 < bi)) { bv = best2; bi = idx2; }
    if (best3 < bv || (best3 == bv && idx3 < bi)) { bv = best3; bi = idx3; }

    const float md = sqrtf(bv);   // sqrt is monotonic: min/argmin on d^2 match reference
    out_md[t]  = md;
    out_idx[t] = bi;

    // Per-batch max(min_dist): wave shuffle reduce -> LDS across 4 waves -> 1 atomic/block.
    float w = md;
    #pragma unroll
    for (int off = 32; off > 0; off >>= 1)
        w = fmaxf(w, __shfl_down(w, off, 64));
    __shared__ float smax[4];
    const int lane = threadIdx.x & 63, wid = threadIdx.x >> 6;
    if (lane == 0) smax[wid] = w;
    __syncthreads();
    if (threadIdx.x == 0) {
        float m4 = fmaxf(fmaxf(smax[0], smax[1]), fmaxf(smax[2], smax[3]));
        // nonneg float bit patterns are order-isomorphic to uint
        atomicMax(bmax + b, __float_as_uint(m4));
    }
}

// Apply the blend: refined = src + alpha*(nearest - src).
// NOTE: src and dst may alias (iteration 2 operates in-place on d_out) -> no
// __restrict__ on src/dst; each thread only touches its own 3 elements.
__global__ __launch_bounds__(256) void update_kernel(
    const float* src,
    const float* __restrict__ partial,
    const float* __restrict__ md_arr,
    const int*   __restrict__ idx_arr,
    const unsigned* __restrict__ bmax,
    float* dst)
{
    const int t = blockIdx.x * 256 + threadIdx.x;
    const int b = t >> 13;
    const float md   = md_arr[t];
    const int   idx  = idx_arr[t];
    const float maxv = __uint_as_float(bmax[b]);
    const float alpha = BASE_ALPHA * (2.0f - md / (maxv + EPS));
    const float* q = partial + 3u * (unsigned)(b * MPART + idx);
    const float* p = src + 3u * (unsigned)t;
    const float px = p[0], py = p[1], pz = p[2];
    const float ox = fmaf(alpha, q[0] - px, px);
    const float oy = fmaf(alpha, q[1] - py, py);
    const float oz = fmaf(alpha, q[2] - pz, pz);
    float* o = dst + 3u * (unsigned)t;
    o[0] = ox; o[1] = oy; o[2] = oz;
}

extern "C" void kernel_launch(void* const* d_in, const int* in_sizes, int n_in,
                              void* d_out, int out_size, void* d_ws, size_t ws_size,
                              hipStream_t stream) {
    const float* pred    = (const float*)d_in[0];   // [8,8192,3] fp32
    const float* partial = (const float*)d_in[1];   // [8,2048,3] fp32
    float* out = (float*)d_out;                     // [8,8192,3] fp32

    char* ws = (char*)d_ws;
    float*    md   = (float*)ws;                        // 65536 floats
    int*      idx  = (int*)(ws + (size_t)NPTS * 4);     // 65536 ints
    unsigned* bmax = (unsigned*)(ws + (size_t)NPTS * 8);// 16 uints (2 iters x 8 batches)

    const int nblk = NPTS / 256;  // 256 blocks -> 1 block/CU, 4 waves/CU

    init_bmax_kernel<<<1, 64, 0, stream>>>(bmax);

    // Iteration 1: pred -> out
    nn_kernel<<<nblk, 256, 0, stream>>>(pred, partial, md, idx, bmax);
    update_kernel<<<nblk, 256, 0, stream>>>(pred, partial, md, idx, bmax, out);

    // Iteration 2: out -> out (in place)
    nn_kernel<<<nblk, 256, 0, stream>>>(out, partial, md, idx, bmax + 8);
    update_kernel<<<nblk, 256, 0, stream>>>(out, partial, md, idx, bmax + 8, out);
}

// Round 2
// 128.453 us; speedup vs baseline: 2.0456x; 2.0456x over previous
//
#include <hip/hip_runtime.h>
#include <math.h>

#define BATCH 8
#define NPRED 8192
#define MPART 2048
#define NPTS  (BATCH * NPRED)   // 65536 query points total
#define SPLIT 4
#define MS    (MPART / SPLIT)   // 512 partial points per wave-split
#define BASE_ALPHA 0.05f
#define EPS 1e-6f

// Zero both per-iteration batch-max slots (8 batches x 2 iterations).
__global__ __launch_bounds__(64) void init_bmax_kernel(unsigned* __restrict__ bmax) {
    if (threadIdx.x < 16) bmax[threadIdx.x] = 0u;
}

// Block = 1024 threads = 16 waves = 4 query-groups x 4 M-splits.
// Each wave: 64 queries (one per lane) scan a wave-uniform 512-point M-range.
// readfirstlane forces the partial base into an SGPR -> s_load_dwordx4 for the
// partial data (scalar cache, zero VMEM/VALU load cost). LDS u64-min merge
// across splits preserves exact (value, first-index) argmin semantics.
__global__ __launch_bounds__(1024) void nn_kernel(
    const float* __restrict__ src,      // [B,N,3] current positions
    const float* __restrict__ partial,  // [B,M,3]
    float* __restrict__ out_md,         // [B*N] min distance (sqrt'd)
    int*   __restrict__ out_idx,        // [B*N] argmin
    unsigned* __restrict__ bmax)        // [B] per-batch max(min_dist) as uint bits
{
    const int qb   = blockIdx.x;          // 256 blocks, 256 queries each
    const int b    = qb >> 5;             // batch (uniform per block)
    const int wave = threadIdx.x >> 6;    // 0..15
    const int lane = threadIdx.x & 63;
    const int qgroup = wave & 3;          // 0..3
    const int split  = wave >> 2;         // 0..3 (uniform per wave)
    const int q    = qgroup * 64 + lane;  // query within block, 0..255
    const int t    = qb * 256 + q;        // global query index

    const float* p = src + 3u * (unsigned)t;
    const float ax = p[0], ay = p[1], az = p[2];

    // Wave-uniform element offset of this wave's M-range; readfirstlane makes
    // it provably uniform so the loop loads below become scalar (s_load).
    int off = 3 * (b * MPART + split * MS);
    off = __builtin_amdgcn_readfirstlane(off);
    const float4* __restrict__ pq4 = (const float4*)(partial + off); // 48B/group, 16B aligned

    float best0 = 1e30f, best1 = 1e30f, best2 = 1e30f, best3 = 1e30f;
    int   bi0 = 0, bi1 = 0, bi2 = 0, bi3 = 0;   // group index of best per chain

    for (int i = 0; i < MS / 4; ++i) {
        const float4 A = pq4[3 * i + 0];
        const float4 B = pq4[3 * i + 1];
        const float4 C = pq4[3 * i + 2];
        {
            float dx = ax - A.x, dy = ay - A.y, dz = az - A.z;
            float d2 = fmaf(dx, dx, fmaf(dy, dy, dz * dz));
            if (d2 < best0) { best0 = d2; bi0 = i; }
        }
        {
            float dx = ax - A.w, dy = ay - B.x, dz = az - B.y;
            float d2 = fmaf(dx, dx, fmaf(dy, dy, dz * dz));
            if (d2 < best1) { best1 = d2; bi1 = i; }
        }
        {
            float dx = ax - B.z, dy = ay - B.w, dz = az - C.x;
            float d2 = fmaf(dx, dx, fmaf(dy, dy, dz * dz));
            if (d2 < best2) { best2 = d2; bi2 = i; }
        }
        {
            float dx = ax - C.y, dy = ay - C.z, dz = az - C.w;
            float d2 = fmaf(dx, dx, fmaf(dy, dy, dz * dz));
            if (d2 < best3) { best3 = d2; bi3 = i; }
        }
    }

    // Merge 4 chains lexicographically (value, then lowest m).
    int m0 = 4 * bi0 + 0, m1 = 4 * bi1 + 1, m2 = 4 * bi2 + 2, m3 = 4 * bi3 + 3;
    float bv = best0; int bm = m0;
    if (best1 < bv || (best1 == bv && m1 < bm)) { bv = best1; bm = m1; }
    if (best2 < bv || (best2 == bv && m2 < bm)) { bv = best2; bm = m2; }
    if (best3 < bv || (best3 == bv && m3 < bm)) { bv = best3; bm = m3; }

    // Pack (d2, global m) -> u64; u64 min == lexicographic (d2, first index)
    // since d2 >= 0 (float bits order-isomorphic to uint).
    const unsigned gm = (unsigned)(split * MS + bm);
    const unsigned long long key =
        ((unsigned long long)__float_as_uint(bv) << 32) | gm;

    __shared__ unsigned long long lkeys[SPLIT * 256]; // [split][query]
    __shared__ float smax[4];
    lkeys[split * 256 + q] = key;
    __syncthreads();

    float wmax = 0.0f;
    if (wave < 4) {
        const int q2 = wave * 64 + lane;       // 0..255
        unsigned long long k0 = lkeys[0 * 256 + q2];
        unsigned long long k1 = lkeys[1 * 256 + q2];
        unsigned long long k2 = lkeys[2 * 256 + q2];
        unsigned long long k3 = lkeys[3 * 256 + q2];
        unsigned long long kk = k0;
        if (k1 < kk) kk = k1;
        if (k2 < kk) kk = k2;
        if (k3 < kk) kk = k3;
        const float md = sqrtf(__uint_as_float((unsigned)(kk >> 32)));
        const int t2 = qb * 256 + q2;
        out_md[t2]  = md;
        out_idx[t2] = (int)(kk & 0xffffffffu);
        // wave max of md
        float w = md;
        #pragma unroll
        for (int o = 32; o > 0; o >>= 1)
            w = fmaxf(w, __shfl_down(w, o, 64));
        if (lane == 0) smax[wave] = w;
        wmax = w;
    }
    (void)wmax;
    __syncthreads();
    if (threadIdx.x == 0) {
        float m4 = fmaxf(fmaxf(smax[0], smax[1]), fmaxf(smax[2], smax[3]));
        atomicMax(bmax + b, __float_as_uint(m4)); // nonneg float bits ~ uint order
    }
}

// refined = src + alpha*(nearest - src). src/dst may alias (in-place iter 2).
__global__ __launch_bounds__(256) void update_kernel(
    const float* src,
    const float* __restrict__ partial,
    const float* __restrict__ md_arr,
    const int*   __restrict__ idx_arr,
    const unsigned* __restrict__ bmax,
    float* dst)
{
    const int t = blockIdx.x * 256 + threadIdx.x;
    const int b = t >> 13;
    const float md   = md_arr[t];
    const int   idx  = idx_arr[t];
    const float maxv = __uint_as_float(bmax[b]);
    const float alpha = BASE_ALPHA * (2.0f - md / (maxv + EPS));
    const float* qq = partial + 3u * (unsigned)(b * MPART + idx);
    const float* pp = src + 3u * (unsigned)t;
    const float px = pp[0], py = pp[1], pz = pp[2];
    const float ox = fmaf(alpha, qq[0] - px, px);
    const float oy = fmaf(alpha, qq[1] - py, py);
    const float oz = fmaf(alpha, qq[2] - pz, pz);
    float* o = dst + 3u * (unsigned)t;
    o[0] = ox; o[1] = oy; o[2] = oz;
}

extern "C" void kernel_launch(void* const* d_in, const int* in_sizes, int n_in,
                              void* d_out, int out_size, void* d_ws, size_t ws_size,
                              hipStream_t stream) {
    const float* pred    = (const float*)d_in[0];   // [8,8192,3] fp32
    const float* partial = (const float*)d_in[1];   // [8,2048,3] fp32
    float* out = (float*)d_out;                     // [8,8192,3] fp32

    char* ws = (char*)d_ws;
    float*    md   = (float*)ws;                         // 65536 floats
    int*      idx  = (int*)(ws + (size_t)NPTS * 4);      // 65536 ints
    unsigned* bmax = (unsigned*)(ws + (size_t)NPTS * 8); // 16 uints (2 iters x 8)

    init_bmax_kernel<<<1, 64, 0, stream>>>(bmax);

    // Iteration 1: pred -> out
    nn_kernel<<<256, 1024, 0, stream>>>(pred, partial, md, idx, bmax);
    update_kernel<<<NPTS / 256, 256, 0, stream>>>(pred, partial, md, idx, bmax, out);

    // Iteration 2: out -> out (in place)
    nn_kernel<<<256, 1024, 0, stream>>>(out, partial, md, idx, bmax + 8);
    update_kernel<<<NPTS / 256, 256, 0, stream>>>(out, partial, md, idx, bmax + 8, out);
}

// Round 3
// 122.163 us; speedup vs baseline: 2.1509x; 1.0515x over previous
//
#include <hip/hip_runtime.h>
#include <math.h>

#define BATCH 8
#define NPRED 8192
#define MPART 2048
#define NPTS  (BATCH * NPRED)      // 65536 queries
#define MTOT  (BATCH * MPART)      // 16384 partial points
#define SPLIT 8
#define MS    (MPART / SPLIT)      // 256 points per wave-split
#define QG    2                    // query groups per block
#define BLOCK_Q (QG * 64)          // 128 queries per block
#define NBLK  (NPTS / BLOCK_Q)     // 512 blocks -> 2 blocks/CU, 8 waves/SIMD
#define BLK_PER_B (NPRED / BLOCK_Q) // 64 blocks per batch
#define BASE_ALPHA 0.05f
#define EPS 1e-6f

// P'[m] = (-2bx,-2by,-2bz,|b|^2): inner loop then needs mul+2fma+add per pair.
// near4[m] = (bx,by,bz,0): single dwordx4 gather for the update step.
__global__ __launch_bounds__(256) void prep_kernel(const float* __restrict__ partial,
                                                   float4* __restrict__ pp,
                                                   float4* __restrict__ near4) {
    const int m = blockIdx.x * 256 + threadIdx.x;   // 64 blocks cover MTOT
    const float* p = partial + 3u * (unsigned)m;
    const float x = p[0], y = p[1], z = p[2];
    pp[m]    = make_float4(-2.0f * x, -2.0f * y, -2.0f * z, fmaf(x, x, fmaf(y, y, z * z)));
    near4[m] = make_float4(x, y, z, 0.0f);
}

// Block = 1024 threads = 16 waves = 2 query-groups x 8 M-splits.
// FUSE: apply the previous iteration's update in the prologue (needs md/idx/
// per-block-max from the previous NN pass) before scanning. md_in/idx_in may
// alias md_out/idx_out: reads happen before the pre-merge __syncthreads,
// writes after, and blocks touch disjoint queries.
template <bool FUSE>
__global__ __launch_bounds__(1024) void nn_kernel(
    const float* __restrict__ src,      // [B,N,3] base positions (pred)
    const float4* __restrict__ pp,      // [B*M] transformed partial (wave-uniform scans)
    const float4* __restrict__ near4,   // [B*M] raw partial, padded
    const float* md_in, const int* idx_in,       // FUSE only (may alias outputs)
    const float* __restrict__ bmax_in,  // [NBLK] per-block max from prev pass (FUSE)
    float* __restrict__ refined_out,    // [B,N,3] refined-1 positions (FUSE)
    float* md_out, int* idx_out,        // [B*N]
    float* __restrict__ bmax_out)       // [NBLK] per-block max(min_dist)
{
    const int qb   = blockIdx.x;
    const int b    = qb / BLK_PER_B;        // uniform per block
    const int wave = threadIdx.x >> 6;
    const int lane = threadIdx.x & 63;
    const int qgroup = wave & (QG - 1);
    const int split  = wave / QG;           // uniform per wave
    const int q    = qgroup * 64 + lane;    // 0..127
    const int t    = qb * BLOCK_Q + q;      // global query index

    __shared__ unsigned long long lkeys[SPLIT * BLOCK_Q];
    __shared__ float smax[QG];
    __shared__ float s_bmax;

    float ax, ay, az;
    if (FUSE) {
        if (threadIdx.x < 64) {   // reduce 64 per-block maxima of this batch
            float v = bmax_in[b * BLK_PER_B + lane];
            #pragma unroll
            for (int o = 32; o > 0; o >>= 1) v = fmaxf(v, __shfl_down(v, o, 64));
            if (lane == 0) s_bmax = v;
        }
        __syncthreads();
        const float maxv = s_bmax;
        const float md = md_in[t];
        const int   id = idx_in[t];
        const float alpha = BASE_ALPHA * (2.0f - md / (maxv + EPS));
        const float4 nb = near4[b * MPART + id];
        const float* p = src + 3u * (unsigned)t;
        const float px = p[0], py = p[1], pz = p[2];
        ax = fmaf(alpha, nb.x - px, px);
        ay = fmaf(alpha, nb.y - py, py);
        az = fmaf(alpha, nb.z - pz, pz);
        if (split == 0) {                    // one copy of refined-1 to ws
            float* o = refined_out + 3u * (unsigned)t;
            o[0] = ax; o[1] = ay; o[2] = az;
        }
    } else {
        const float* p = src + 3u * (unsigned)t;
        ax = p[0]; ay = p[1]; az = p[2];
    }
    const float a2 = fmaf(ax, ax, fmaf(ay, ay, az * az));

    // Wave-uniform scan base -> s_load of P' (scalar cache).
    int off = b * MPART + split * MS;
    off = __builtin_amdgcn_readfirstlane(off);
    const float4* __restrict__ q4 = pp + off;

    // Track h = |b|^2 - 2 a.b  (= d^2 - |a|^2; same ordering, same expansion
    // arithmetic as the reference's a2 - 2ab + b2). 4 chains for ILP.
    float h0 = 1e30f, h1 = 1e30f, h2 = 1e30f, h3 = 1e30f;
    int bi0 = 0, bi1 = 0, bi2 = 0, bi3 = 0;
    #pragma unroll 4
    for (int i = 0; i < MS / 4; ++i) {
        const float4 P0 = q4[4 * i + 0];
        const float4 P1 = q4[4 * i + 1];
        const float4 P2 = q4[4 * i + 2];
        const float4 P3 = q4[4 * i + 3];
        { float s = fmaf(P0.x, ax, fmaf(P0.y, ay, P0.z * az)); float v = s + P0.w;
          if (v < h0) { h0 = v; bi0 = i; } }
        { float s = fmaf(P1.x, ax, fmaf(P1.y, ay, P1.z * az)); float v = s + P1.w;
          if (v < h1) { h1 = v; bi1 = i; } }
        { float s = fmaf(P2.x, ax, fmaf(P2.y, ay, P2.z * az)); float v = s + P2.w;
          if (v < h2) { h2 = v; bi2 = i; } }
        { float s = fmaf(P3.x, ax, fmaf(P3.y, ay, P3.z * az)); float v = s + P3.w;
          if (v < h3) { h3 = v; bi3 = i; } }
    }

    // Lexicographic merge (h, then lowest m) across chains.
    const int m0 = 4 * bi0, m1 = 4 * bi1 + 1, m2 = 4 * bi2 + 2, m3 = 4 * bi3 + 3;
    float bv = h0; int bm = m0;
    if (h1 < bv || (h1 == bv && m1 < bm)) { bv = h1; bm = m1; }
    if (h2 < bv || (h2 == bv && m2 < bm)) { bv = h2; bm = m2; }
    if (h3 < bv || (h3 == bv && m3 < bm)) { bv = h3; bm = m3; }
    const float d2 = fmaxf(bv + a2, 0.0f);   // nonneg -> float bits uint-ordered
    const unsigned gm = (unsigned)(split * MS + bm);
    lkeys[split * BLOCK_Q + q] =
        ((unsigned long long)__float_as_uint(d2) << 32) | gm;
    __syncthreads();

    // Cross-split merge: u64 min == lexicographic (d2, first index).
    if (wave < QG) {
        const int q2 = wave * 64 + lane;
        unsigned long long kk = lkeys[q2];
        #pragma unroll
        for (int s = 1; s < SPLIT; ++s) {
            const unsigned long long k = lkeys[s * BLOCK_Q + q2];
            if (k < kk) kk = k;
        }
        const float md = sqrtf(__uint_as_float((unsigned)(kk >> 32)));
        const int t2 = qb * BLOCK_Q + q2;
        md_out[t2]  = md;
        idx_out[t2] = (int)(kk & 0xffffffffu);
        float w = md;
        #pragma unroll
        for (int o = 32; o > 0; o >>= 1) w = fmaxf(w, __shfl_down(w, o, 64));
        if (lane == 0) smax[wave] = w;
    }
    __syncthreads();
    if (threadIdx.x == 0) bmax_out[qb] = fmaxf(smax[0], smax[1]);
}

// Final blend: out = refined1 + alpha2*(nearest2 - refined1).
__global__ __launch_bounds__(256) void update_kernel(
    const float* __restrict__ refined1,
    const float4* __restrict__ near4,
    const float* __restrict__ md2,
    const int*   __restrict__ idx2,
    const float* __restrict__ bmax2,   // [NBLK]
    float* __restrict__ out)
{
    __shared__ float s_bmax;
    const int t = blockIdx.x * 256 + threadIdx.x;
    const int b = t >> 13;             // 32 blocks per batch -> uniform
    if (threadIdx.x < 64) {
        float v = bmax2[b * BLK_PER_B + threadIdx.x];
        #pragma unroll
        for (int o = 32; o > 0; o >>= 1) v = fmaxf(v, __shfl_down(v, o, 64));
        if (threadIdx.x == 0) s_bmax = v;
    }
    __syncthreads();
    const float maxv = s_bmax;
    const float md = md2[t];
    const int   id = idx2[t];
    const float alpha = BASE_ALPHA * (2.0f - md / (maxv + EPS));
    const float4 nb = near4[b * MPART + id];
    const float* p = refined1 + 3u * (unsigned)t;
    const float px = p[0], py = p[1], pz = p[2];
    float* o = out + 3u * (unsigned)t;
    o[0] = fmaf(alpha, nb.x - px, px);
    o[1] = fmaf(alpha, nb.y - py, py);
    o[2] = fmaf(alpha, nb.z - pz, pz);
}

extern "C" void kernel_launch(void* const* d_in, const int* in_sizes, int n_in,
                              void* d_out, int out_size, void* d_ws, size_t ws_size,
                              hipStream_t stream) {
    const float* pred    = (const float*)d_in[0];   // [8,8192,3] fp32
    const float* partial = (const float*)d_in[1];   // [8,2048,3] fp32
    float* out = (float*)d_out;

    char* ws = (char*)d_ws;                 // layout (16B-aligned first):
    float4* pp    = (float4*)ws;                         // 256 KB
    float4* near4 = (float4*)(ws + 262144);              // 256 KB
    float*  ref1  = (float*)(ws + 524288);               // 768 KB
    float*  md1   = (float*)(ws + 1310720);              // 256 KB
    int*    idx1  = (int*)(ws + 1572864);                // 256 KB
    float*  bmax1 = (float*)(ws + 1835008);              // 2 KB
    float*  bmax2 = bmax1 + NBLK;                        // 2 KB

    prep_kernel<<<MTOT / 256, 256, 0, stream>>>(partial, pp, near4);

    // Iter 1 NN: pred -> md1/idx1/bmax1
    nn_kernel<false><<<NBLK, 1024, 0, stream>>>(
        pred, pp, near4, nullptr, nullptr, nullptr, nullptr, md1, idx1, bmax1);

    // Iter 1 update fused with iter 2 NN: writes ref1, overwrites md1/idx1
    // (safe: per-block reads precede writes across a __syncthreads).
    nn_kernel<true><<<NBLK, 1024, 0, stream>>>(
        pred, pp, near4, md1, idx1, bmax1, ref1, md1, idx1, bmax2);

    // Iter 2 update: ref1 -> out
    update_kernel<<<NPTS / 256, 256, 0, stream>>>(ref1, near4, md1, idx1, bmax2, out);
}

// Round 4
// 99.245 us; speedup vs baseline: 2.6476x; 1.2309x over previous
//
#include <hip/hip_runtime.h>
#include <math.h>

#define BATCH 8
#define NPRED 8192
#define MPART 2048
#define NPTS  (BATCH * NPRED)      // 65536 queries
#define MTOT  (BATCH * MPART)      // 16384 partial points
#define QPL   4                    // queries per lane
#define SPLIT 16                   // 16 waves = 16 M-splits per block
#define PTS_PER_SPLIT (MPART / SPLIT)   // 128
#define GPS   (PTS_PER_SPLIT / 4)       // 32 groups of 4 points per split
#define QPB   256                  // queries per block (4 qpl * 64 lanes)
#define NBLK  (NPTS / QPB)         // 256 blocks
#define BLK_PER_B (NPRED / QPB)    // 32 blocks per batch
#define BASE_ALPHA 0.05f
#define EPS 1e-6f

// Grouped-SoA P': for each group g of 4 points, 4 consecutive float4s:
//   ppg[4g+0]={-2x0..-2x3} ppg[4g+1]={-2y..} ppg[4g+2]={-2z..} ppg[4g+3]={|b|^2..}
// near4[m] = (x,y,z,0) for the single-float4 nearest gather in updates.
__global__ __launch_bounds__(256) void prep_kernel(const float* __restrict__ partial,
                                                   float* __restrict__ ppgf,
                                                   float4* __restrict__ near4) {
    const int m = blockIdx.x * 256 + threadIdx.x;   // 64 blocks cover MTOT
    const float* p = partial + 3u * (unsigned)m;
    const float x = p[0], y = p[1], z = p[2];
    const int g = m >> 2, c = m & 3;
    float* base = ppgf + (size_t)g * 16 + c;
    base[0]  = -2.0f * x;
    base[4]  = -2.0f * y;
    base[8]  = -2.0f * z;
    base[12] = fmaf(x, x, fmaf(y, y, z * z));
    near4[m] = make_float4(x, y, z, 0.0f);
}

// Block = 1024 threads = 16 waves. Wave w scans M-split w (128 pts) for the
// block's 256 queries (4 per lane). P' staged in LDS (32 KB); inner reads are
// wave-uniform broadcasts (conflict-free, in-order lgkm partial waits).
// Grouped argmin: loop tracks (group-min, group-id) only; epilogue reloads the
// winning group and recomputes the 4 dots with IDENTICAL fp ops (bit-exact) to
// recover the element index; strict '<' + lowest-c tie-break = first-occurrence.
// FUSE: apply previous iteration's blend in the prologue (round-3 pattern).
template <bool FUSE>
__global__ __launch_bounds__(1024) void nn_kernel(
    const float* __restrict__ src,      // [B,N,3] base positions
    const float4* __restrict__ ppg,     // [MTOT] grouped-SoA P'
    const float4* __restrict__ near4,   // [MTOT] raw partial
    const float* md_in, const int* idx_in,   // FUSE only (may alias outputs)
    const float* __restrict__ bmax_in,  // [NBLK] per-block max from prev pass
    float* __restrict__ refined_out,    // [B,N,3] (FUSE)
    float* md_out, int* idx_out,        // [B*N]
    float* __restrict__ bmax_out)       // [NBLK]
{
    __shared__ float4 ldsP[2048];       // 32 KB; later overlaid as 4096 u64 keys
    __shared__ float smax[4];
    unsigned long long* lk = (unsigned long long*)ldsP;

    const int qb   = blockIdx.x;
    const int b    = qb >> 5;               // 32 blocks per batch
    const int tid  = threadIdx.x;
    const int wave = tid >> 6, lane = tid & 63;
    const int split = wave;

    // Stage this batch's P' tile (2048 float4) into LDS, coalesced.
    const float4* gsrc = ppg + ((size_t)b << 11);
    ldsP[tid]        = gsrc[tid];
    ldsP[tid + 1024] = gsrc[tid + 1024];

    // Load / compute the 4 per-lane query positions.
    float axq[QPL], ayq[QPL], azq[QPL], a2q[QPL];
    if (FUSE) {
        float v = bmax_in[(b << 5) + (lane & 31)];
        #pragma unroll
        for (int o = 32; o > 0; o >>= 1) v = fmaxf(v, __shfl_down(v, o, 64));
        const float maxv = __shfl(v, 0, 64);
        #pragma unroll
        for (int j = 0; j < QPL; ++j) {
            const int t = (qb << 8) + (j << 6) + lane;
            const float md = md_in[t];
            const int   id = idx_in[t];
            const float alpha = BASE_ALPHA * (2.0f - md / (maxv + EPS));
            const float4 nb = near4[((size_t)b << 11) + id];
            const float* p = src + 3u * (unsigned)t;
            const float px = p[0], py = p[1], pz = p[2];
            axq[j] = fmaf(alpha, nb.x - px, px);
            ayq[j] = fmaf(alpha, nb.y - py, py);
            azq[j] = fmaf(alpha, nb.z - pz, pz);
            if (split == 0) {               // one copy of refined-1 to ws
                float* o = refined_out + 3u * (unsigned)t;
                o[0] = axq[j]; o[1] = ayq[j]; o[2] = azq[j];
            }
        }
    } else {
        #pragma unroll
        for (int j = 0; j < QPL; ++j) {
            const int t = (qb << 8) + (j << 6) + lane;
            const float* p = src + 3u * (unsigned)t;
            axq[j] = p[0]; ayq[j] = p[1]; azq[j] = p[2];
        }
    }
    #pragma unroll
    for (int j = 0; j < QPL; ++j)
        a2q[j] = fmaf(axq[j], axq[j], fmaf(ayq[j], ayq[j], azq[j] * azq[j]));

    __syncthreads();   // LDS tile ready

    const float4* wp = ldsP + split * (GPS * 4);   // this wave's 128 float4
    float best[QPL]; int bg[QPL];
    #pragma unroll
    for (int j = 0; j < QPL; ++j) { best[j] = 1e30f; bg[j] = 0; }

    #pragma unroll 2
    for (int i = 0; i < GPS; ++i) {
        const float4 X = wp[4 * i + 0];
        const float4 Y = wp[4 * i + 1];
        const float4 Z = wp[4 * i + 2];
        const float4 W = wp[4 * i + 3];
        #pragma unroll
        for (int j = 0; j < QPL; ++j) {
            const float ax = axq[j], ay = ayq[j], az = azq[j];
            const float d0 = fmaf(Z.x, az, fmaf(Y.x, ay, X.x * ax)) + W.x;
            const float d1 = fmaf(Z.y, az, fmaf(Y.y, ay, X.y * ax)) + W.y;
            const float d2 = fmaf(Z.z, az, fmaf(Y.z, ay, X.z * ax)) + W.z;
            const float d3 = fmaf(Z.w, az, fmaf(Y.w, ay, X.w * ax)) + W.w;
            const float gm = fminf(fminf(fminf(d0, d1), d2), d3);
            if (gm < best[j]) bg[j] = i;       // strict <: earliest group wins
            best[j] = fminf(best[j], gm);
        }
    }

    // Epilogue: recover element index within the winning group (bit-exact
    // recompute; fminf returns one operand exactly, so an equality must hit).
    unsigned long long key[QPL];
    #pragma unroll
    for (int j = 0; j < QPL; ++j) {
        const int gi = bg[j];
        const float4 X = wp[4 * gi + 0];
        const float4 Y = wp[4 * gi + 1];
        const float4 Z = wp[4 * gi + 2];
        const float4 W = wp[4 * gi + 3];
        const float ax = axq[j], ay = ayq[j], az = azq[j];
        const float d0 = fmaf(Z.x, az, fmaf(Y.x, ay, X.x * ax)) + W.x;
        const float d1 = fmaf(Z.y, az, fmaf(Y.y, ay, X.y * ax)) + W.y;
        const float d2 = fmaf(Z.z, az, fmaf(Y.z, ay, X.z * ax)) + W.z;
        const float bv = best[j];
        int c;
        if      (d0 == bv) c = 0;
        else if (d1 == bv) c = 1;
        else if (d2 == bv) c = 2;
        else               c = 3;
        const int m = (split << 7) + (gi << 2) + c;   // index within batch
        const float dd = fmaxf(bv + a2q[j], 0.0f);    // nonneg -> uint-ordered
        key[j] = ((unsigned long long)__float_as_uint(dd) << 32) | (unsigned)m;
    }

    __syncthreads();   // all LDS tile reads done; safe to overlay with keys
    #pragma unroll
    for (int j = 0; j < QPL; ++j)
        lk[split * QPB + (j << 6) + lane] = key[j];
    __syncthreads();

    // Cross-split merge: u64 min == lexicographic (d^2, first index).
    if (wave < 4) {
        const int q2 = (wave << 6) + lane;   // 0..255
        unsigned long long kk = lk[q2];
        #pragma unroll
        for (int s = 1; s < SPLIT; ++s) {
            const unsigned long long k = lk[s * QPB + q2];
            if (k < kk) kk = k;
        }
        const float md = sqrtf(__uint_as_float((unsigned)(kk >> 32)));
        const int t2 = (qb << 8) + q2;
        md_out[t2]  = md;
        idx_out[t2] = (int)(kk & 0xffffffffu);
        float w = md;
        #pragma unroll
        for (int o = 32; o > 0; o >>= 1) w = fmaxf(w, __shfl_down(w, o, 64));
        if (lane == 0) smax[wave] = w;
    }
    __syncthreads();
    if (tid == 0)
        bmax_out[qb] = fmaxf(fmaxf(smax[0], smax[1]), fmaxf(smax[2], smax[3]));
}

// Final blend: out = refined1 + alpha2*(nearest2 - refined1).
__global__ __launch_bounds__(256) void update_kernel(
    const float* __restrict__ refined1,
    const float4* __restrict__ near4,
    const float* __restrict__ md2,
    const int*   __restrict__ idx2,
    const float* __restrict__ bmax2,   // [NBLK]
    float* __restrict__ out)
{
    const int t = blockIdx.x * 256 + threadIdx.x;
    const int b = t >> 13;
    const int lane = threadIdx.x & 63;
    float v = bmax2[(b << 5) + (lane & 31)];
    #pragma unroll
    for (int o = 32; o > 0; o >>= 1) v = fmaxf(v, __shfl_down(v, o, 64));
    const float maxv = __shfl(v, 0, 64);
    const float md = md2[t];
    const int   id = idx2[t];
    const float alpha = BASE_ALPHA * (2.0f - md / (maxv + EPS));
    const float4 nb = near4[((size_t)b << 11) + id];
    const float* p = refined1 + 3u * (unsigned)t;
    const float px = p[0], py = p[1], pz = p[2];
    float* o = out + 3u * (unsigned)t;
    o[0] = fmaf(alpha, nb.x - px, px);
    o[1] = fmaf(alpha, nb.y - py, py);
    o[2] = fmaf(alpha, nb.z - pz, pz);
}

extern "C" void kernel_launch(void* const* d_in, const int* in_sizes, int n_in,
                              void* d_out, int out_size, void* d_ws, size_t ws_size,
                              hipStream_t stream) {
    const float* pred    = (const float*)d_in[0];   // [8,8192,3] fp32
    const float* partial = (const float*)d_in[1];   // [8,2048,3] fp32
    float* out = (float*)d_out;

    char* ws = (char*)d_ws;                          // 16B-aligned chunks first
    float4* ppg   = (float4*)ws;                     // 256 KB grouped-SoA P'
    float4* near4 = (float4*)(ws + 262144);          // 256 KB
    float*  ref1  = (float*)(ws + 524288);           // 768 KB
    float*  md1   = (float*)(ws + 1310720);          // 256 KB
    int*    idx1  = (int*)(ws + 1572864);            // 256 KB
    float*  bmax1 = (float*)(ws + 1835008);          // 1 KB
    float*  bmax2 = bmax1 + NBLK;                    // 1 KB

    prep_kernel<<<MTOT / 256, 256, 0, stream>>>(partial, (float*)ppg, near4);

    // Iter 1 NN: pred -> md1/idx1/bmax1
    nn_kernel<false><<<NBLK, 1024, 0, stream>>>(
        pred, ppg, near4, nullptr, nullptr, nullptr, nullptr, md1, idx1, bmax1);

    // Iter 1 update fused into iter 2 NN: writes ref1, overwrites md1/idx1.
    nn_kernel<true><<<NBLK, 1024, 0, stream>>>(
        pred, ppg, near4, md1, idx1, bmax1, ref1, md1, idx1, bmax2);

    // Iter 2 update: ref1 -> out
    update_kernel<<<NPTS / 256, 256, 0, stream>>>(ref1, near4, md1, idx1, bmax2, out);
}